// Round 3
// baseline (1724.636 us; speedup 1.0000x reference)
//
#include <hip/hip_runtime.h>
#include <math.h>
#include <stdint.h>

#define EMBS 32
#define INS 64
#define HS 128
#define OUTS 256
#define BS 64
#define SS 2048

typedef _Float16 half2v __attribute__((ext_vector_type(2)));

// ws layout (4B elems): emb [B][S][IN] f32 | dist [B][IN] f32 | hfin [B][H] f32 | xw [B][S][512] f16
static constexpr size_t WS_DIST  = (size_t)BS * SS * INS;
static constexpr size_t WS_HFIN  = WS_DIST + (size_t)BS * INS;
static constexpr size_t WS_XW    = WS_HFIN + (size_t)BS * HS;
static constexpr size_t WS_SMALL = WS_XW;                         // elems without xw
static constexpr size_t WS_BIG   = WS_XW + (size_t)BS * SS * 256; // elems with xw (512 f16 = 256 u32 / row)

__device__ __forceinline__ float fexp2(float x) {
#if __has_builtin(__builtin_amdgcn_exp2f)
    return __builtin_amdgcn_exp2f(x);
#else
    return exp2f(x);
#endif
}
__device__ __forceinline__ float frcp(float x) {
#if __has_builtin(__builtin_amdgcn_rcpf)
    return __builtin_amdgcn_rcpf(x);
#else
    return 1.f / x;
#endif
}
__device__ __forceinline__ float sigm(float x)  { return frcp(1.f + fexp2(-1.44269504f * x)); }
__device__ __forceinline__ float ftanh(float x) { return 1.f - 2.f * frcp(1.f + fexp2(2.88539008f * x)); }

__device__ __forceinline__ float fdot2f(half2v a, half2v b, float c) {
#if __has_builtin(__builtin_amdgcn_fdot2)
    return __builtin_amdgcn_fdot2(a, b, c, false);
#else
    return c + (float)a.x * (float)b.x + (float)a.y * (float)b.y;
#endif
}

__device__ __forceinline__ half2v pack2(float a, float b) {
    half2v r; r.x = (_Float16)a; r.y = (_Float16)b; return r;
}

// ---------------------------------------------------------------------------
// K1: byte-decompose + embedding gather + encoder MLP (both pc and addr)
// ---------------------------------------------------------------------------
__global__ __launch_bounds__(256) void k_embed(
    const int* __restrict__ inp, const float* __restrict__ pc_emb,
    const float* __restrict__ ad_emb, const float* __restrict__ encW,
    const float* __restrict__ encB, float* __restrict__ emb)
{
    int idx = blockIdx.x * 256 + threadIdx.x;
    int b = idx >> 11, t = idx & 2047;
    size_t base = (size_t)b * SS + t;
    int2 pa = ((const int2*)inp)[base];
    float* outp = emb + base * INS;

    float in[128];
    #pragma unroll
    for (int st = 0; st < 2; st++) {
        int v = (st == 0) ? pa.x : pa.y;
        const float* tbl = (st == 0) ? pc_emb : ad_emb;
        #pragma unroll
        for (int i = 0; i < 4; i++) {
            int by = (v >> (24 - 8 * i)) & 255;
            const float4* row = (const float4*)(tbl + ((size_t)i * 256 + by) * EMBS);
            #pragma unroll
            for (int k = 0; k < 8; k++) {
                float4 f = row[k];
                in[i * 32 + k * 4 + 0] = f.x;
                in[i * 32 + k * 4 + 1] = f.y;
                in[i * 32 + k * 4 + 2] = f.z;
                in[i * 32 + k * 4 + 3] = f.w;
            }
        }
        for (int e = 0; e < EMBS; e++) {
            const float* w = encW + e * 128;
            float acc = encB[e];
            #pragma unroll
            for (int k = 0; k < 128; k++) acc += in[k] * w[k];
            outp[st * EMBS + e] = sigm(acc);
        }
    }
}

// ---------------------------------------------------------------------------
// K2: dist[b][j] = mean over t of emb[b][t][j]
// ---------------------------------------------------------------------------
__global__ __launch_bounds__(256) void k_dist(const float* __restrict__ emb,
                                              float* __restrict__ dist)
{
    int b = blockIdx.x;
    int j = threadIdx.x & 63;
    int grp = threadIdx.x >> 6;
    float s = 0.f;
    for (int t = grp; t < SS; t += 4) s += emb[((size_t)b * SS + t) * INS + j];
    __shared__ float red[4][64];
    red[grp][j] = s;
    __syncthreads();
    if (grp == 0)
        dist[b * 64 + j] = (red[0][j] + red[1][j] + red[2][j] + red[3][j]) * (1.f / SS);
}

// ---------------------------------------------------------------------------
// K_XW: xw[row][u][4] f16, gate order [i, g, f, o] per unit.
// Block stages 64 x-rows in LDS (1 barrier), then barrier-free dot loop.
// thread: u = tid&127, sel = tid>>7. sel0 -> gates (i, g); sel1 -> (f, o).
// ---------------------------------------------------------------------------
#define XW_ROWS 64
__global__ __launch_bounds__(256) void k_xw(
    const float* __restrict__ emb, const float* __restrict__ Wih,
    const float* __restrict__ bih, const float* __restrict__ bhh,
    half2v* __restrict__ xwv)      // [row][256] half2v
{
    int tid = threadIdx.x;
    size_t r0 = (size_t)blockIdx.x * XW_ROWS;
    int u = tid & 127, sel = tid >> 7;
    int gA = sel ? 128 + u : u;          // f : i
    int gB = sel ? 384 + u : 256 + u;    // o : g

    half2v wa[32], wb[32];
    const float* pa_ = Wih + (size_t)gA * INS;
    const float* pb_ = Wih + (size_t)gB * INS;
    #pragma unroll
    for (int i = 0; i < 32; i++) {
        wa[i] = pack2(pa_[2 * i], pa_[2 * i + 1]);
        wb[i] = pack2(pb_[2 * i], pb_[2 * i + 1]);
    }
    float ba = bih[gA] + bhh[gA], bb = bih[gB] + bhh[gB];

    __shared__ alignas(16) half2v xsh[XW_ROWS * 32];   // 8 KiB
    const float4* src = (const float4*)(emb + r0 * INS);
    #pragma unroll
    for (int k = 0; k < 4; k++) {
        int fi = k * 256 + tid;
        float4 v = src[fi];
        xsh[fi * 2]     = pack2(v.x, v.y);
        xsh[fi * 2 + 1] = pack2(v.z, v.w);
    }
    __syncthreads();

    #pragma unroll 2
    for (int r = 0; r < XW_ROWS; r++) {
        const half2v* xr = &xsh[r * 32];
        float a0 = 0.f, a1 = 0.f, b0 = 0.f, b1 = 0.f;
        #pragma unroll
        for (int i = 0; i < 32; i += 2) {
            half2v x0 = xr[i], x1 = xr[i + 1];
            a0 = fdot2f(x0, wa[i], a0);
            a1 = fdot2f(x1, wa[i + 1], a1);
            b0 = fdot2f(x0, wb[i], b0);
            b1 = fdot2f(x1, wb[i + 1], b1);
        }
        xwv[(r0 + r) * 256 + u * 2 + sel] = pack2(ba + a0 + a1, bb + b0 + b1);
    }
}

// ---------------------------------------------------------------------------
// K3: LSTM, 512 threads/block, K-split-4. Thread (u = tid>>2, q = tid&3):
//   computes 4 gate-partials over K-quarter q, reduce-scatter via DPP
//   shfl_xor(1/2) -> thread q owns gate q (0=i,1=f,2=g,3=o), activation,
//   all-gather via shfl, replicated c/h update. 1 raw s_barrier per step,
//   lgkmcnt(0) only (global xw prefetch, 3 deep, stays in flight).
// ---------------------------------------------------------------------------
__global__ __launch_bounds__(512, 1) void k_lstm3(
    const uint2* __restrict__ xwq,   // [B*S][128] b64: per unit [i,g,f,o] f16
    const float* __restrict__ h0, const float* __restrict__ c0,
    const float* __restrict__ Whh, float* __restrict__ hfin)
{
    int b = blockIdx.x;
    int tid = threadIdx.x;
    int u = tid >> 2, q = tid & 3;
    bool qb0 = (q & 1), qb1 = (q & 2);

    // weights: 4 gate rows (i,f,g,o) x my K-quarter, f16 pairs
    half2v w0[16], w1[16], w2[16], w3[16];
    {
        const float* r0_ = Whh + (size_t)(u)       * HS + q * 32;
        const float* r1_ = Whh + (size_t)(128 + u) * HS + q * 32;
        const float* r2_ = Whh + (size_t)(256 + u) * HS + q * 32;
        const float* r3_ = Whh + (size_t)(384 + u) * HS + q * 32;
        #pragma unroll
        for (int i = 0; i < 16; i++) {
            w0[i] = pack2(r0_[2 * i], r0_[2 * i + 1]);
            w1[i] = pack2(r1_[2 * i], r1_[2 * i + 1]);
            w2[i] = pack2(r2_[2 * i], r2_[2 * i + 1]);
            w3[i] = pack2(r3_[2 * i], r3_[2 * i + 1]);
        }
    }

    // per-thread constants for branchless activation (gate q: 2=g -> tanh)
    float zm  = (q == 2) ? -2.88539008f : -1.44269504f;  // exp2 scale
    float sc  = (q == 2) ? 2.f : 1.f;                    // act = sc*y - (sc-1)
    float off = 1.f - sc;
    // xw f16 position per gate: [i,g,f,o] -> q0:0, q1:2, q2:1, q3:3
    int pos = ((q & 1) << 1) | (q >> 1);
    int xw_hi = pos >> 1;
    int xw_sh = (pos & 1) * 16;

    __shared__ alignas(16) _Float16 hsh[2][HS];
    float c = c0[b * HS + u];          // replicated across the 4 q-threads
    if (tid < 128) hsh[0][tid] = (_Float16)h0[b * HS + tid];
    __syncthreads();

    const uint2* xrow = xwq + (size_t)b * SS * 128 + u;
    uint2 xa = xrow[0 * 128ll * 0 + 0];        // t=0
    xa = xrow[0];
    uint2 x1 = xrow[1 * (size_t)128];
    uint2 x2 = xrow[2 * (size_t)128];

    int p = 0;
    float h = 0.f;
    for (int t = 0; t < SS; t++) {
        // issue prefetch t+3 (stays in flight across the raw barrier)
        int tn = (t + 3 < SS) ? (t + 3) : (SS - 1);
        uint2 xn = xrow[(size_t)tn * 128];

        // LDS read: my K-quarter of h (4 x ds_read_b128)
        half2v hr[16];
        const half2v* hb = (const half2v*)&hsh[p][q * 32];
        #pragma unroll
        for (int j = 0; j < 16; j++) hr[j] = hb[j];

        // 4 gate-partials, 16-deep chains
        float pa = 0.f, pb = 0.f, pg = 0.f, pd = 0.f;
        #pragma unroll
        for (int j = 0; j < 16; j++) {
            half2v hv = hr[j];
            pa = fdot2f(hv, w0[j], pa);
            pb = fdot2f(hv, w1[j], pb);
            pg = fdot2f(hv, w2[j], pg);
            pd = fdot2f(hv, w3[j], pd);
        }
        // select p[q^k] without runtime array indexing (rule #20)
        float pq  = qb1 ? (qb0 ? pd : pg) : (qb0 ? pb : pa);
        float pq1 = qb1 ? (qb0 ? pg : pd) : (qb0 ? pa : pb);
        float pq2 = qb1 ? (qb0 ? pb : pa) : (qb0 ? pd : pg);
        float pq3 = qb1 ? (qb0 ? pa : pb) : (qb0 ? pg : pd);

        // reduce-scatter: thread q ends with full sum for gate q
        float sq  = pq  + __shfl_xor(pq1, 1, 64);
        float sq2 = pq2 + __shfl_xor(pq3, 1, 64);
        float S   = sq  + __shfl_xor(sq2, 2, 64);

        // + xw (extract my gate's f16 from the b64 loaded 3 steps ago)
        unsigned wsel = xw_hi ? xa.y : xa.x;
        unsigned short hbits = (unsigned short)(wsel >> xw_sh);
        float pre = S + (float)__builtin_bit_cast(_Float16, hbits);

        // branchless activation: sigm for i,f,o; tanh for g
        float y = frcp(1.f + fexp2(zm * pre));
        float act = __builtin_fmaf(sc, y, off);

        // all-gather the 4 activations
        float a1 = __shfl_xor(act, 1, 64);
        float a2 = __shfl_xor(act, 2, 64);
        float a3 = __shfl_xor(a1, 2, 64);

        // i*g, f, o via parity selects
        float ig = qb0 ? a1 * a3 : act * a2;
        float fg = qb0 ? (qb1 ? a2 : act) : (qb1 ? a3 : a1);
        float og = qb0 ? (qb1 ? act : a2) : (qb1 ? a1 : a3);

        c = __builtin_fmaf(fg, c, ig);
        h = og * ftanh(c);
        if (q == 0) hsh[p ^ 1][u] = (_Float16)h;

        // LDS-only drain + raw barrier: xw prefetch NOT drained
        asm volatile("s_waitcnt lgkmcnt(0)" ::: "memory");
        __builtin_amdgcn_s_barrier();
        __builtin_amdgcn_sched_barrier(0);

        p ^= 1;
        xa = x1; x1 = x2; x2 = xn;
    }
    if (q == 0) hfin[b * HS + u] = h;
}

// ---------------------------------------------------------------------------
// K3 (fallback, ws too small for xW): round-1 structure, fast activations
// ---------------------------------------------------------------------------
__global__ __launch_bounds__(256, 1) void k_lstm_fb(
    const float* __restrict__ emb, const float* __restrict__ h0,
    const float* __restrict__ c0, const float* __restrict__ Wih,
    const float* __restrict__ Whh, const float* __restrict__ bih,
    const float* __restrict__ bhh, float* __restrict__ hfin)
{
    int b = blockIdx.x;
    int tid = threadIdx.x;

    half2v wih[2][32], whh[2][64];
    #pragma unroll
    for (int g = 0; g < 2; g++) {
        int gg = tid + g * 256;
        const float* wr = Wih + (size_t)gg * INS;
        #pragma unroll
        for (int i = 0; i < 32; i++) wih[g][i] = pack2(wr[2 * i], wr[2 * i + 1]);
        const float* hr = Whh + (size_t)gg * HS;
        #pragma unroll
        for (int i = 0; i < 64; i++) whh[g][i] = pack2(hr[2 * i], hr[2 * i + 1]);
    }
    float bias0 = bih[tid] + bhh[tid];
    float bias1 = bih[tid + 256] + bhh[tid + 256];

    __shared__ alignas(16) half2v xh[96];
    __shared__ float f_act[128], o_act[128];
    __shared__ float xf[64], hf[128];

    float c = 0.f, h = 0.f;
    if (tid < 128) c = c0[b * HS + tid];

    const float* xrow = emb + (size_t)b * SS * INS;
    if (tid < 64) xf[tid] = xrow[tid];
    if (tid < 128) hf[tid] = h0[b * HS + tid];
    __syncthreads();
    if (tid < 32) xh[tid] = pack2(xf[2 * tid], xf[2 * tid + 1]);
    else if (tid < 96) { int uu = tid - 32; xh[tid] = pack2(hf[2 * uu], hf[2 * uu + 1]); }
    __syncthreads();

    for (int t = 0; t < SS; t++) {
        float xn = 0.f;
        if (tid >= 128 && tid < 192 && t + 1 < SS) xn = xrow[(size_t)(t + 1) * INS + (tid - 128)];

        float a0a = 0.f, a0b = 0.f, a1a = 0.f, a1b = 0.f;
        #pragma unroll
        for (int i = 0; i < 32; i += 2) {
            half2v x0 = xh[i], x1 = xh[i + 1];
            a0a = fdot2f(x0, wih[0][i], a0a);
            a0b = fdot2f(x1, wih[0][i + 1], a0b);
            a1a = fdot2f(x0, wih[1][i], a1a);
            a1b = fdot2f(x1, wih[1][i + 1], a1b);
        }
        #pragma unroll
        for (int i = 0; i < 64; i += 2) {
            half2v h0v = xh[32 + i], h1v = xh[32 + i + 1];
            a0a = fdot2f(h0v, whh[0][i], a0a);
            a0b = fdot2f(h1v, whh[0][i + 1], a0b);
            a1a = fdot2f(h0v, whh[1][i], a1a);
            a1b = fdot2f(h1v, whh[1][i + 1], a1b);
        }
        float a0 = bias0 + a0a + a0b;
        float a1 = bias1 + a1a + a1b;

        float iact = 0.f, gact = 0.f;
        if (tid < 128) { iact = sigm(a0); gact = ftanh(a1); }
        else           { f_act[tid - 128] = sigm(a0); o_act[tid - 128] = sigm(a1); }
        __syncthreads();

        if (tid < 128) {
            c = f_act[tid] * c + iact * gact;
            h = o_act[tid] * ftanh(c);
            hf[tid] = h;
        } else if (tid < 192) {
            xf[tid - 128] = xn;
        }
        __syncthreads();

        if (tid < 32) xh[tid] = pack2(xf[2 * tid], xf[2 * tid + 1]);
        else if (tid < 96) { int uu = tid - 32; xh[tid] = pack2(hf[2 * uu], hf[2 * uu + 1]); }
        __syncthreads();
    }
    if (tid < 128) hfin[b * HS + tid] = h;
}

// ---------------------------------------------------------------------------
// K4: decoder logits + T=1e-3 softmax + freq-rec head. one block per b.
// ---------------------------------------------------------------------------
__global__ __launch_bounds__(256) void k_head(
    const float* __restrict__ hfin, const float* __restrict__ decW,
    const float* __restrict__ decB, const float* __restrict__ ad_emb,
    const float* __restrict__ encW, const float* __restrict__ encB,
    const float* __restrict__ dist, const float* __restrict__ fc1W,
    const float* __restrict__ fc1b, const float* __restrict__ fc2W,
    const float* __restrict__ fc2b, float* __restrict__ outp)
{
    int b = blockIdx.x;
    int tid = threadIdx.x;
    __shared__ float hsh[128];
    __shared__ float logit_s[4][256];
    __shared__ float probs_s[4][256];
    __shared__ float be_s[128];
    __shared__ float fe_dist[96];
    __shared__ float fr1[10];

    if (tid < 128) hsh[tid] = hfin[b * HS + tid];
    __syncthreads();

    #pragma unroll
    for (int k = 0; k < 4; k++) {
        const float* w = decW + ((size_t)k * OUTS + tid) * HS;
        float acc = decB[k * OUTS + tid];
        #pragma unroll 8
        for (int hh = 0; hh < HS; hh++) acc += hsh[hh] * w[hh];
        logit_s[k][tid] = acc;
        outp[65536 + k * 16384 + b * 256 + tid] = acc;
    }
    __syncthreads();

    {
        int k = tid >> 6, lane = tid & 63;
        float v0 = logit_s[k][lane],       v1 = logit_s[k][lane + 64];
        float v2 = logit_s[k][lane + 128], v3 = logit_s[k][lane + 192];
        float m = fmaxf(fmaxf(v0, v1), fmaxf(v2, v3));
        for (int off = 32; off; off >>= 1) m = fmaxf(m, __shfl_xor(m, off, 64));
        float e0 = fexp2((v0 - m) * 1442.695041f), e1 = fexp2((v1 - m) * 1442.695041f);
        float e2 = fexp2((v2 - m) * 1442.695041f), e3 = fexp2((v3 - m) * 1442.695041f);
        float s = e0 + e1 + e2 + e3;
        for (int off = 32; off; off >>= 1) s += __shfl_xor(s, off, 64);
        float inv = 1.f / s;
        float p0 = e0 * inv, p1 = e1 * inv, p2 = e2 * inv, p3 = e3 * inv;
        probs_s[k][lane] = p0;        probs_s[k][lane + 64] = p1;
        probs_s[k][lane + 128] = p2;  probs_s[k][lane + 192] = p3;
        outp[k * 16384 + b * 256 + lane] = p0;
        outp[k * 16384 + b * 256 + lane + 64] = p1;
        outp[k * 16384 + b * 256 + lane + 128] = p2;
        outp[k * 16384 + b * 256 + lane + 192] = p3;
    }
    __syncthreads();

    if (tid < 128) {
        int k = tid >> 5, e = tid & 31;
        const float* te = ad_emb + (size_t)k * OUTS * EMBS + e;
        float acc = 0.f;
        #pragma unroll 8
        for (int o = 0; o < OUTS; o++) acc += probs_s[k][o] * te[o * EMBS];
        be_s[tid] = acc;
    }
    __syncthreads();

    if (tid < 32) {
        const float* w = encW + tid * 128;
        float acc = encB[tid];
        #pragma unroll 8
        for (int kk = 0; kk < 128; kk++) acc += be_s[kk] * w[kk];
        fe_dist[tid] = sigm(acc);
    } else if (tid < 96) {
        fe_dist[tid] = dist[b * 64 + (tid - 32)];
    }
    __syncthreads();

    if (tid < 10) {
        float acc = fc1b[tid];
        for (int kk = 0; kk < 96; kk++) acc += fe_dist[kk] * fc1W[tid * 96 + kk];
        fr1[tid] = fmaxf(acc, 0.f);
    }
    __syncthreads();

    if (tid < 2) {
        float acc = fc2b[tid];
        for (int kk = 0; kk < 10; kk++) acc += fr1[kk] * fc2W[tid * 10 + kk];
        outp[131072 + tid * 64 + b] = sigm(acc);
    }
}

// ---------------------------------------------------------------------------
extern "C" void kernel_launch(void* const* d_in, const int* in_sizes, int n_in,
                              void* d_out, int out_size, void* d_ws, size_t ws_size,
                              hipStream_t stream)
{
    const int*   inp    = (const int*)d_in[0];
    const float* h0     = (const float*)d_in[1];
    const float* c0     = (const float*)d_in[2];
    const float* pc_emb = (const float*)d_in[3];
    const float* ad_emb = (const float*)d_in[4];
    const float* encW   = (const float*)d_in[5];
    const float* encB   = (const float*)d_in[6];
    const float* Wih    = (const float*)d_in[7];
    const float* Whh    = (const float*)d_in[8];
    const float* bih    = (const float*)d_in[9];
    const float* bhh    = (const float*)d_in[10];
    const float* decW   = (const float*)d_in[11];
    const float* decB   = (const float*)d_in[12];
    const float* fc1W   = (const float*)d_in[13];
    const float* fc1b   = (const float*)d_in[14];
    const float* fc2W   = (const float*)d_in[15];
    const float* fc2b   = (const float*)d_in[16];

    if (ws_size < WS_SMALL * 4ull) return;

    float* ws   = (float*)d_ws;
    float* emb  = ws;
    float* dist = ws + WS_DIST;
    float* hfin = ws + WS_HFIN;
    float* outp = (float*)d_out;
    bool big = (ws_size >= WS_BIG * 4ull);

    hipLaunchKernelGGL(k_embed, dim3(512), dim3(256), 0, stream,
                       inp, pc_emb, ad_emb, encW, encB, emb);
    hipLaunchKernelGGL(k_dist, dim3(64), dim3(256), 0, stream, emb, dist);
    if (big) {
        half2v* xwv = (half2v*)(ws + WS_XW);
        hipLaunchKernelGGL(k_xw, dim3(BS * SS / XW_ROWS), dim3(256), 0, stream,
                           emb, Wih, bih, bhh, xwv);
        hipLaunchKernelGGL(k_lstm3, dim3(64), dim3(512), 0, stream,
                           (const uint2*)xwv, h0, c0, Whh, hfin);
    } else {
        hipLaunchKernelGGL(k_lstm_fb, dim3(64), dim3(256), 0, stream,
                           emb, h0, c0, Wih, Whh, bih, bhh, hfin);
    }
    hipLaunchKernelGGL(k_head, dim3(64), dim3(256), 0, stream,
                       hfin, decW, decB, ad_emb, encW, encB, dist,
                       fc1W, fc1b, fc2W, fc2b, outp);
}

// Round 4
// 1582.146 us; speedup vs baseline: 1.0901x; 1.0901x over previous
//
#include <hip/hip_runtime.h>
#include <math.h>
#include <stdint.h>

#define EMBS 32
#define INS 64
#define HS 128
#define OUTS 256
#define BS 64
#define SS 2048

typedef _Float16 half2v __attribute__((ext_vector_type(2)));

// ws layout (4B elems): emb [B][S][IN] f32 | dist [B][IN] f32 | hfin [B][H] f32 | xw [B][S][256] half2v
static constexpr size_t WS_DIST  = (size_t)BS * SS * INS;
static constexpr size_t WS_HFIN  = WS_DIST + (size_t)BS * INS;
static constexpr size_t WS_XW    = WS_HFIN + (size_t)BS * HS;
static constexpr size_t WS_SMALL = WS_XW;
static constexpr size_t WS_BIG   = WS_XW + (size_t)BS * SS * 256;

__device__ __forceinline__ float fexp2(float x) {
#if __has_builtin(__builtin_amdgcn_exp2f)
    return __builtin_amdgcn_exp2f(x);
#else
    return exp2f(x);
#endif
}
__device__ __forceinline__ float frcp(float x) {
#if __has_builtin(__builtin_amdgcn_rcpf)
    return __builtin_amdgcn_rcpf(x);
#else
    return 1.f / x;
#endif
}
__device__ __forceinline__ float sigm(float x)  { return frcp(1.f + fexp2(-1.44269504f * x)); }
__device__ __forceinline__ float ftanh(float x) { return 1.f - 2.f * frcp(1.f + fexp2(2.88539008f * x)); }

__device__ __forceinline__ float fdot2f(half2v a, half2v b, float c) {
#if __has_builtin(__builtin_amdgcn_fdot2)
    return __builtin_amdgcn_fdot2(a, b, c, false);
#else
    return c + (float)a.x * (float)b.x + (float)a.y * (float)b.y;
#endif
}

__device__ __forceinline__ half2v pack2(float a, float b) {
    half2v r; r.x = (_Float16)a; r.y = (_Float16)b; return r;
}

// shared gate mapping (k_xw writer == k_lstm4 reader, indexed by tid):
// lane l<32: unit u, gates (i_u, g_u) = rows (u, 256+u)
// lane l>=32: unit u, gates (f_u, o_u) = rows (128+u, 384+u)
// u = (tid>>6)*32 + (l&31)
__device__ __forceinline__ void gate_map(int tid, int& u, bool& lo, int& g0, int& g1) {
    int l = tid & 63;
    u = ((tid >> 6) << 5) + (l & 31);
    lo = (l < 32);
    g0 = lo ? u : 128 + u;
    g1 = lo ? 256 + u : 384 + u;
}

// ---------------------------------------------------------------------------
// K1: byte-decompose + embedding gather + encoder MLP (both pc and addr)
// ---------------------------------------------------------------------------
__global__ __launch_bounds__(256) void k_embed(
    const int* __restrict__ inp, const float* __restrict__ pc_emb,
    const float* __restrict__ ad_emb, const float* __restrict__ encW,
    const float* __restrict__ encB, float* __restrict__ emb)
{
    int idx = blockIdx.x * 256 + threadIdx.x;
    int b = idx >> 11, t = idx & 2047;
    size_t base = (size_t)b * SS + t;
    int2 pa = ((const int2*)inp)[base];
    float* outp = emb + base * INS;

    float in[128];
    #pragma unroll
    for (int st = 0; st < 2; st++) {
        int v = (st == 0) ? pa.x : pa.y;
        const float* tbl = (st == 0) ? pc_emb : ad_emb;
        #pragma unroll
        for (int i = 0; i < 4; i++) {
            int by = (v >> (24 - 8 * i)) & 255;
            const float4* row = (const float4*)(tbl + ((size_t)i * 256 + by) * EMBS);
            #pragma unroll
            for (int k = 0; k < 8; k++) {
                float4 f = row[k];
                in[i * 32 + k * 4 + 0] = f.x;
                in[i * 32 + k * 4 + 1] = f.y;
                in[i * 32 + k * 4 + 2] = f.z;
                in[i * 32 + k * 4 + 3] = f.w;
            }
        }
        for (int e = 0; e < EMBS; e++) {
            const float* w = encW + e * 128;
            float acc = encB[e];
            #pragma unroll
            for (int k = 0; k < 128; k++) acc += in[k] * w[k];
            outp[st * EMBS + e] = sigm(acc);
        }
    }
}

// ---------------------------------------------------------------------------
// K2: dist[b][j] = mean over t of emb[b][t][j]
// ---------------------------------------------------------------------------
__global__ __launch_bounds__(256) void k_dist(const float* __restrict__ emb,
                                              float* __restrict__ dist)
{
    int b = blockIdx.x;
    int j = threadIdx.x & 63;
    int grp = threadIdx.x >> 6;
    float s = 0.f;
    for (int t = grp; t < SS; t += 4) s += emb[((size_t)b * SS + t) * INS + j];
    __shared__ float red[4][64];
    red[grp][j] = s;
    __syncthreads();
    if (grp == 0)
        dist[b * 64 + j] = (red[0][j] + red[1][j] + red[2][j] + red[3][j]) * (1.f / SS);
}

// ---------------------------------------------------------------------------
// K_XW: xw[row][tid] = pack2(g0-row dot x + biases, g1-row dot x + biases)
// Stages 64 x-rows in LDS once (1 barrier), then barrier-free dot loop.
// ---------------------------------------------------------------------------
#define XW_ROWS 64
__global__ __launch_bounds__(256) void k_xw(
    const float* __restrict__ emb, const float* __restrict__ Wih,
    const float* __restrict__ bih, const float* __restrict__ bhh,
    half2v* __restrict__ xwv)      // [row][256] half2v
{
    int tid = threadIdx.x;
    size_t r0 = (size_t)blockIdx.x * XW_ROWS;
    int u, g0, g1; bool lo;
    gate_map(tid, u, lo, g0, g1);

    half2v wa[32], wb[32];
    const float* pa_ = Wih + (size_t)g0 * INS;
    const float* pb_ = Wih + (size_t)g1 * INS;
    #pragma unroll
    for (int i = 0; i < 32; i++) {
        wa[i] = pack2(pa_[2 * i], pa_[2 * i + 1]);
        wb[i] = pack2(pb_[2 * i], pb_[2 * i + 1]);
    }
    float ba = bih[g0] + bhh[g0], bb = bih[g1] + bhh[g1];

    __shared__ alignas(16) half2v xsh[XW_ROWS * 32];   // 8 KiB
    const float4* src = (const float4*)(emb + r0 * INS);
    #pragma unroll
    for (int k = 0; k < 4; k++) {
        int fi = k * 256 + tid;
        float4 v = src[fi];
        xsh[fi * 2]     = pack2(v.x, v.y);
        xsh[fi * 2 + 1] = pack2(v.z, v.w);
    }
    __syncthreads();

    #pragma unroll 2
    for (int r = 0; r < XW_ROWS; r++) {
        const half2v* xr = &xsh[r * 32];
        float a0 = 0.f, a1 = 0.f, b0 = 0.f, b1 = 0.f;
        #pragma unroll
        for (int i = 0; i < 32; i += 2) {
            half2v x0 = xr[i], x1 = xr[i + 1];
            a0 = fdot2f(x0, wa[i], a0);
            a1 = fdot2f(x1, wa[i + 1], a1);
            b0 = fdot2f(x0, wb[i], b0);
            b1 = fdot2f(x1, wb[i + 1], b1);
        }
        xwv[(r0 + r) * 256 + tid] = pack2(ba + a0 + a1, bb + b0 + b1);
    }
}

// ---------------------------------------------------------------------------
// K3: LSTM. 256 threads, pair-split gates (R2 structure), with:
//  - raw s_barrier (lgkmcnt(0) only) -> 4-deep xw prefetch never drained
//  - single shfl (ig lo->hi); hi lanes own c and the h update
// ---------------------------------------------------------------------------
__global__ __launch_bounds__(256, 1) void k_lstm4(
    const half2v* __restrict__ xw, const float* __restrict__ h0,
    const float* __restrict__ c0, const float* __restrict__ Whh,
    float* __restrict__ hfin)
{
    int b = blockIdx.x;
    int tid = threadIdx.x;
    int u, g0, g1; bool lo;
    gate_map(tid, u, lo, g0, g1);

    // W_hh rows for my two gates, packed f16 in VGPRs (128 VGPRs)
    half2v wh0[64], wh1[64];
    const float* h0p = Whh + (size_t)g0 * HS;
    const float* h1p = Whh + (size_t)g1 * HS;
    #pragma unroll
    for (int i = 0; i < 64; i++) {
        wh0[i] = pack2(h0p[2 * i], h0p[2 * i + 1]);
        wh1[i] = pack2(h1p[2 * i], h1p[2 * i + 1]);
    }

    __shared__ alignas(16) _Float16 hsh[2][HS];
    float c = 0.f, h = 0.f;
    if (!lo) c = c0[b * HS + u];           // hi lanes own the c state
    if (tid < 128) hsh[0][tid] = (_Float16)h0[b * HS + tid];
    __syncthreads();

    const half2v* xwrow = xw + (size_t)b * SS * 256 + tid;
    // 4-deep rotating prefetch (named regs; rule #20)
    half2v x0 = xwrow[0];
    half2v x1 = xwrow[256];
    half2v x2 = xwrow[512];
    half2v x3 = xwrow[768];

    int p = 0;
    for (int t = 0; t < SS; t++) {
        int tn = (t + 4 < SS) ? (t + 4) : (SS - 1);
        half2v xn = xwrow[(size_t)tn * 256];   // stays in flight across barrier

        const half2v* hr = (const half2v*)hsh[p];
        float a0a = 0.f, a0b = 0.f, a1a = 0.f, a1b = 0.f;
        #pragma unroll
        for (int i = 0; i < 64; i += 2) {
            half2v h0v = hr[i], h1v = hr[i + 1];
            a0a = fdot2f(h0v, wh0[i], a0a);
            a0b = fdot2f(h1v, wh0[i + 1], a0b);
            a1a = fdot2f(h0v, wh1[i], a1a);
            a1b = fdot2f(h1v, wh1[i + 1], a1b);
        }
        float a0 = (float)x0.x + a0a + a0b;
        float a1 = (float)x0.y + a1a + a1b;

        // lo: act0=sigm(i), act1=tanh(g) | hi: act0=sigm(f), act1=sigm(o)
        float act0 = sigm(a0);
        float act1 = lo ? ftanh(a1) : sigm(a1);
        float ig = act0 * act1;                 // lo: i*g (hi: f*o, unused)
        float pig = __shfl_xor(ig, 32, 64);     // hi receives lo's i*g

        if (!lo) {
            c = __builtin_fmaf(act0, c, pig);   // c = f*c + i*g
            h = act1 * ftanh(c);                // h = o*tanh(c)
            hsh[p ^ 1][u] = (_Float16)h;
        }

        // LDS-only drain + raw barrier: global prefetch NOT drained
        asm volatile("s_waitcnt lgkmcnt(0)" ::: "memory");
        __builtin_amdgcn_s_barrier();
        __builtin_amdgcn_sched_barrier(0);

        p ^= 1;
        x0 = x1; x1 = x2; x2 = x3; x3 = xn;
    }
    if (!lo) hfin[b * HS + u] = h;
}

// ---------------------------------------------------------------------------
// K3 (fallback, ws too small for xW)
// ---------------------------------------------------------------------------
__global__ __launch_bounds__(256, 1) void k_lstm_fb(
    const float* __restrict__ emb, const float* __restrict__ h0,
    const float* __restrict__ c0, const float* __restrict__ Wih,
    const float* __restrict__ Whh, const float* __restrict__ bih,
    const float* __restrict__ bhh, float* __restrict__ hfin)
{
    int b = blockIdx.x;
    int tid = threadIdx.x;

    half2v wih[2][32], whh[2][64];
    #pragma unroll
    for (int g = 0; g < 2; g++) {
        int gg = tid + g * 256;
        const float* wr = Wih + (size_t)gg * INS;
        #pragma unroll
        for (int i = 0; i < 32; i++) wih[g][i] = pack2(wr[2 * i], wr[2 * i + 1]);
        const float* hr = Whh + (size_t)gg * HS;
        #pragma unroll
        for (int i = 0; i < 64; i++) whh[g][i] = pack2(hr[2 * i], hr[2 * i + 1]);
    }
    float bias0 = bih[tid] + bhh[tid];
    float bias1 = bih[tid + 256] + bhh[tid + 256];

    __shared__ alignas(16) half2v xh[96];
    __shared__ float f_act[128], o_act[128];
    __shared__ float xf[64], hf[128];

    float c = 0.f, h = 0.f;
    if (tid < 128) c = c0[b * HS + tid];

    const float* xrow = emb + (size_t)b * SS * INS;
    if (tid < 64) xf[tid] = xrow[tid];
    if (tid < 128) hf[tid] = h0[b * HS + tid];
    __syncthreads();
    if (tid < 32) xh[tid] = pack2(xf[2 * tid], xf[2 * tid + 1]);
    else if (tid < 96) { int uu = tid - 32; xh[tid] = pack2(hf[2 * uu], hf[2 * uu + 1]); }
    __syncthreads();

    for (int t = 0; t < SS; t++) {
        float xn = 0.f;
        if (tid >= 128 && tid < 192 && t + 1 < SS) xn = xrow[(size_t)(t + 1) * INS + (tid - 128)];

        float a0a = 0.f, a0b = 0.f, a1a = 0.f, a1b = 0.f;
        #pragma unroll
        for (int i = 0; i < 32; i += 2) {
            half2v x0 = xh[i], x1 = xh[i + 1];
            a0a = fdot2f(x0, wih[0][i], a0a);
            a0b = fdot2f(x1, wih[0][i + 1], a0b);
            a1a = fdot2f(x0, wih[1][i], a1a);
            a1b = fdot2f(x1, wih[1][i + 1], a1b);
        }
        #pragma unroll
        for (int i = 0; i < 64; i += 2) {
            half2v h0v = xh[32 + i], h1v = xh[32 + i + 1];
            a0a = fdot2f(h0v, whh[0][i], a0a);
            a0b = fdot2f(h1v, whh[0][i + 1], a0b);
            a1a = fdot2f(h0v, whh[1][i], a1a);
            a1b = fdot2f(h1v, whh[1][i + 1], a1b);
        }
        float a0 = bias0 + a0a + a0b;
        float a1 = bias1 + a1a + a1b;

        float iact = 0.f, gact = 0.f;
        if (tid < 128) { iact = sigm(a0); gact = ftanh(a1); }
        else           { f_act[tid - 128] = sigm(a0); o_act[tid - 128] = sigm(a1); }
        __syncthreads();

        if (tid < 128) {
            c = f_act[tid] * c + iact * gact;
            h = o_act[tid] * ftanh(c);
            hf[tid] = h;
        } else if (tid < 192) {
            xf[tid - 128] = xn;
        }
        __syncthreads();

        if (tid < 32) xh[tid] = pack2(xf[2 * tid], xf[2 * tid + 1]);
        else if (tid < 96) { int uu = tid - 32; xh[tid] = pack2(hf[2 * uu], hf[2 * uu + 1]); }
        __syncthreads();
    }
    if (tid < 128) hfin[b * HS + tid] = h;
}

// ---------------------------------------------------------------------------
// K4: decoder logits + T=1e-3 softmax + freq-rec head. one block per b.
// ---------------------------------------------------------------------------
__global__ __launch_bounds__(256) void k_head(
    const float* __restrict__ hfin, const float* __restrict__ decW,
    const float* __restrict__ decB, const float* __restrict__ ad_emb,
    const float* __restrict__ encW, const float* __restrict__ encB,
    const float* __restrict__ dist, const float* __restrict__ fc1W,
    const float* __restrict__ fc1b, const float* __restrict__ fc2W,
    const float* __restrict__ fc2b, float* __restrict__ outp)
{
    int b = blockIdx.x;
    int tid = threadIdx.x;
    __shared__ float hsh[128];
    __shared__ float logit_s[4][256];
    __shared__ float probs_s[4][256];
    __shared__ float be_s[128];
    __shared__ float fe_dist[96];
    __shared__ float fr1[10];

    if (tid < 128) hsh[tid] = hfin[b * HS + tid];
    __syncthreads();

    #pragma unroll
    for (int k = 0; k < 4; k++) {
        const float* w = decW + ((size_t)k * OUTS + tid) * HS;
        float acc = decB[k * OUTS + tid];
        #pragma unroll 8
        for (int hh = 0; hh < HS; hh++) acc += hsh[hh] * w[hh];
        logit_s[k][tid] = acc;
        outp[65536 + k * 16384 + b * 256 + tid] = acc;
    }
    __syncthreads();

    {
        int k = tid >> 6, lane = tid & 63;
        float v0 = logit_s[k][lane],       v1 = logit_s[k][lane + 64];
        float v2 = logit_s[k][lane + 128], v3 = logit_s[k][lane + 192];
        float m = fmaxf(fmaxf(v0, v1), fmaxf(v2, v3));
        for (int off = 32; off; off >>= 1) m = fmaxf(m, __shfl_xor(m, off, 64));
        float e0 = fexp2((v0 - m) * 1442.695041f), e1 = fexp2((v1 - m) * 1442.695041f);
        float e2 = fexp2((v2 - m) * 1442.695041f), e3 = fexp2((v3 - m) * 1442.695041f);
        float s = e0 + e1 + e2 + e3;
        for (int off = 32; off; off >>= 1) s += __shfl_xor(s, off, 64);
        float inv = 1.f / s;
        float p0 = e0 * inv, p1 = e1 * inv, p2 = e2 * inv, p3 = e3 * inv;
        probs_s[k][lane] = p0;        probs_s[k][lane + 64] = p1;
        probs_s[k][lane + 128] = p2;  probs_s[k][lane + 192] = p3;
        outp[k * 16384 + b * 256 + lane] = p0;
        outp[k * 16384 + b * 256 + lane + 64] = p1;
        outp[k * 16384 + b * 256 + lane + 128] = p2;
        outp[k * 16384 + b * 256 + lane + 192] = p3;
    }
    __syncthreads();

    if (tid < 128) {
        int k = tid >> 5, e = tid & 31;
        const float* te = ad_emb + (size_t)k * OUTS * EMBS + e;
        float acc = 0.f;
        #pragma unroll 8
        for (int o = 0; o < OUTS; o++) acc += probs_s[k][o] * te[o * EMBS];
        be_s[tid] = acc;
    }
    __syncthreads();

    if (tid < 32) {
        const float* w = encW + tid * 128;
        float acc = encB[tid];
        #pragma unroll 8
        for (int kk = 0; kk < 128; kk++) acc += be_s[kk] * w[kk];
        fe_dist[tid] = sigm(acc);
    } else if (tid < 96) {
        fe_dist[tid] = dist[b * 64 + (tid - 32)];
    }
    __syncthreads();

    if (tid < 10) {
        float acc = fc1b[tid];
        for (int kk = 0; kk < 96; kk++) acc += fe_dist[kk] * fc1W[tid * 96 + kk];
        fr1[tid] = fmaxf(acc, 0.f);
    }
    __syncthreads();

    if (tid < 2) {
        float acc = fc2b[tid];
        for (int kk = 0; kk < 10; kk++) acc += fr1[kk] * fc2W[tid * 10 + kk];
        outp[131072 + tid * 64 + b] = sigm(acc);
    }
}

// ---------------------------------------------------------------------------
extern "C" void kernel_launch(void* const* d_in, const int* in_sizes, int n_in,
                              void* d_out, int out_size, void* d_ws, size_t ws_size,
                              hipStream_t stream)
{
    const int*   inp    = (const int*)d_in[0];
    const float* h0     = (const float*)d_in[1];
    const float* c0     = (const float*)d_in[2];
    const float* pc_emb = (const float*)d_in[3];
    const float* ad_emb = (const float*)d_in[4];
    const float* encW   = (const float*)d_in[5];
    const float* encB   = (const float*)d_in[6];
    const float* Wih    = (const float*)d_in[7];
    const float* Whh    = (const float*)d_in[8];
    const float* bih    = (const float*)d_in[9];
    const float* bhh    = (const float*)d_in[10];
    const float* decW   = (const float*)d_in[11];
    const float* decB   = (const float*)d_in[12];
    const float* fc1W   = (const float*)d_in[13];
    const float* fc1b   = (const float*)d_in[14];
    const float* fc2W   = (const float*)d_in[15];
    const float* fc2b   = (const float*)d_in[16];

    if (ws_size < WS_SMALL * 4ull) return;

    float* ws   = (float*)d_ws;
    float* emb  = ws;
    float* dist = ws + WS_DIST;
    float* hfin = ws + WS_HFIN;
    float* outp = (float*)d_out;
    bool big = (ws_size >= WS_BIG * 4ull);

    hipLaunchKernelGGL(k_embed, dim3(512), dim3(256), 0, stream,
                       inp, pc_emb, ad_emb, encW, encB, emb);
    hipLaunchKernelGGL(k_dist, dim3(64), dim3(256), 0, stream, emb, dist);
    if (big) {
        half2v* xwv = (half2v*)(ws + WS_XW);
        hipLaunchKernelGGL(k_xw, dim3(BS * SS / XW_ROWS), dim3(256), 0, stream,
                           emb, Wih, bih, bhh, xwv);
        hipLaunchKernelGGL(k_lstm4, dim3(64), dim3(256), 0, stream,
                           xwv, h0, c0, Whh, hfin);
    } else {
        hipLaunchKernelGGL(k_lstm_fb, dim3(64), dim3(256), 0, stream,
                           emb, h0, c0, Wih, Whh, bih, bhh, hfin);
    }
    hipLaunchKernelGGL(k_head, dim3(64), dim3(256), 0, stream,
                       hfin, decW, decB, ad_emb, encW, encB, dist,
                       fc1W, fc1b, fc2W, fc2b, outp);
}

// Round 6
// 1497.396 us; speedup vs baseline: 1.1518x; 1.0566x over previous
//
#include <hip/hip_runtime.h>
#include <math.h>
#include <stdint.h>

#define EMBS 32
#define INS 64
#define HS 128
#define OUTS 256
#define BS 64
#define SS 2048

typedef _Float16 half2v __attribute__((ext_vector_type(2)));

// ws layout (4B elems): emb [B][S][IN] f32 | dist [B][IN] f32 | hfin [B][H] f32 | xw [B][S][256] half2v
static constexpr size_t WS_DIST  = (size_t)BS * SS * INS;
static constexpr size_t WS_HFIN  = WS_DIST + (size_t)BS * INS;
static constexpr size_t WS_XW    = WS_HFIN + (size_t)BS * HS;
static constexpr size_t WS_SMALL = WS_XW;
static constexpr size_t WS_BIG   = WS_XW + (size_t)BS * SS * 256;

__device__ __forceinline__ float fexp2(float x) {
#if __has_builtin(__builtin_amdgcn_exp2f)
    return __builtin_amdgcn_exp2f(x);
#else
    return exp2f(x);
#endif
}
__device__ __forceinline__ float frcp(float x) {
#if __has_builtin(__builtin_amdgcn_rcpf)
    return __builtin_amdgcn_rcpf(x);
#else
    return 1.f / x;
#endif
}
__device__ __forceinline__ float sigm(float x)  { return frcp(1.f + fexp2(-1.44269504f * x)); }
__device__ __forceinline__ float ftanh(float x) { return 1.f - 2.f * frcp(1.f + fexp2(2.88539008f * x)); }

__device__ __forceinline__ float fdot2f(half2v a, half2v b, float c) {
#if __has_builtin(__builtin_amdgcn_fdot2)
    return __builtin_amdgcn_fdot2(a, b, c, false);
#else
    return c + (float)a.x * (float)b.x + (float)a.y * (float)b.y;
#endif
}

__device__ __forceinline__ half2v pack2(float a, float b) {
    half2v r; r.x = (_Float16)a; r.y = (_Float16)b; return r;
}

// shared gate mapping (k_xw writer == k_lstm reader, indexed by tid):
// lane l<32: unit u, xw = (i_u, g_u) | lane l>=32: unit u, xw = (f_u, o_u)
// u = (tid>>6)*32 + (l&31)
__device__ __forceinline__ void gate_map(int tid, int& u, bool& lo, int& g0, int& g1) {
    int l = tid & 63;
    u = ((tid >> 6) << 5) + (l & 31);
    lo = (l < 32);
    g0 = lo ? u : 128 + u;
    g1 = lo ? 256 + u : 384 + u;
}

// ---------------------------------------------------------------------------
// K1: byte-decompose + embedding gather + encoder MLP (both pc and addr)
// ---------------------------------------------------------------------------
__global__ __launch_bounds__(256) void k_embed(
    const int* __restrict__ inp, const float* __restrict__ pc_emb,
    const float* __restrict__ ad_emb, const float* __restrict__ encW,
    const float* __restrict__ encB, float* __restrict__ emb)
{
    int idx = blockIdx.x * 256 + threadIdx.x;
    int b = idx >> 11, t = idx & 2047;
    size_t base = (size_t)b * SS + t;
    int2 pa = ((const int2*)inp)[base];
    float* outp = emb + base * INS;

    float in[128];
    #pragma unroll
    for (int st = 0; st < 2; st++) {
        int v = (st == 0) ? pa.x : pa.y;
        const float* tbl = (st == 0) ? pc_emb : ad_emb;
        #pragma unroll
        for (int i = 0; i < 4; i++) {
            int by = (v >> (24 - 8 * i)) & 255;
            const float4* row = (const float4*)(tbl + ((size_t)i * 256 + by) * EMBS);
            #pragma unroll
            for (int k = 0; k < 8; k++) {
                float4 f = row[k];
                in[i * 32 + k * 4 + 0] = f.x;
                in[i * 32 + k * 4 + 1] = f.y;
                in[i * 32 + k * 4 + 2] = f.z;
                in[i * 32 + k * 4 + 3] = f.w;
            }
        }
        for (int e = 0; e < EMBS; e++) {
            const float* w = encW + e * 128;
            float acc = encB[e];
            #pragma unroll
            for (int k = 0; k < 128; k++) acc += in[k] * w[k];
            outp[st * EMBS + e] = sigm(acc);
        }
    }
}

// ---------------------------------------------------------------------------
// K2: dist[b][j] = mean over t of emb[b][t][j]
// ---------------------------------------------------------------------------
__global__ __launch_bounds__(256) void k_dist(const float* __restrict__ emb,
                                              float* __restrict__ dist)
{
    int b = blockIdx.x;
    int j = threadIdx.x & 63;
    int grp = threadIdx.x >> 6;
    float s = 0.f;
    for (int t = grp; t < SS; t += 4) s += emb[((size_t)b * SS + t) * INS + j];
    __shared__ float red[4][64];
    red[grp][j] = s;
    __syncthreads();
    if (grp == 0)
        dist[b * 64 + j] = (red[0][j] + red[1][j] + red[2][j] + red[3][j]) * (1.f / SS);
}

// ---------------------------------------------------------------------------
// K_XW: xw[row][tid] = pack2(g0-row dot x + biases, g1-row dot x + biases)
// ---------------------------------------------------------------------------
#define XW_ROWS 64
__global__ __launch_bounds__(256) void k_xw(
    const float* __restrict__ emb, const float* __restrict__ Wih,
    const float* __restrict__ bih, const float* __restrict__ bhh,
    half2v* __restrict__ xwv)      // [row][256] half2v
{
    int tid = threadIdx.x;
    size_t r0 = (size_t)blockIdx.x * XW_ROWS;
    int u, g0, g1; bool lo;
    gate_map(tid, u, lo, g0, g1);

    half2v wa[32], wb[32];
    const float* pa_ = Wih + (size_t)g0 * INS;
    const float* pb_ = Wih + (size_t)g1 * INS;
    #pragma unroll
    for (int i = 0; i < 32; i++) {
        wa[i] = pack2(pa_[2 * i], pa_[2 * i + 1]);
        wb[i] = pack2(pb_[2 * i], pb_[2 * i + 1]);
    }
    float ba = bih[g0] + bhh[g0], bb = bih[g1] + bhh[g1];

    __shared__ alignas(16) half2v xsh[XW_ROWS * 32];   // 8 KiB
    const float4* src = (const float4*)(emb + r0 * INS);
    #pragma unroll
    for (int k = 0; k < 4; k++) {
        int fi = k * 256 + tid;
        float4 v = src[fi];
        xsh[fi * 2]     = pack2(v.x, v.y);
        xsh[fi * 2 + 1] = pack2(v.z, v.w);
    }
    __syncthreads();

    #pragma unroll 2
    for (int r = 0; r < XW_ROWS; r++) {
        const half2v* xr = &xsh[r * 32];
        float a0 = 0.f, a1 = 0.f, b0 = 0.f, b1 = 0.f;
        #pragma unroll
        for (int i = 0; i < 32; i += 2) {
            half2v x0 = xr[i], x1 = xr[i + 1];
            a0 = fdot2f(x0, wa[i], a0);
            a1 = fdot2f(x1, wa[i + 1], a1);
            b0 = fdot2f(x0, wb[i], b0);
            b1 = fdot2f(x1, wb[i + 1], b1);
        }
        xwv[(r0 + r) * 256 + tid] = pack2(ba + a0 + a1, bb + b0 + b1);
    }
}

// ---------------------------------------------------------------------------
// K3: LSTM. K-split-2 per lane pair (lanes l / l^32 share unit u), exchanges
// via proven __shfl_xor(.,32,64). Unroll-4 with rotation-free prefetch regs:
// each xb reg is used then reloaded for t+4 -> load->use distance = 4 steps,
// so the raw-barrier (lgkmcnt-only) never forces a vmcnt drain.
// ---------------------------------------------------------------------------
__global__ __launch_bounds__(256, 1) void k_lstm6(
    const half2v* __restrict__ xw, const float* __restrict__ h0,
    const float* __restrict__ c0, const float* __restrict__ Whh,
    float* __restrict__ hfin)
{
    int b = blockIdx.x;
    int tid = threadIdx.x;
    int u, g0_, g1_; bool lo;
    gate_map(tid, u, lo, g0_, g1_);
    int koff = lo ? 0 : 64;        // my K-half (f16 elements)
    int kv   = lo ? 0 : 32;        // same, in half2v units

    // all 4 gate rows of unit u, my K-half: 4 x 32 half2v = 128 VGPRs
    half2v wI[32], wF[32], wG[32], wO[32];
    {
        const float* rI = Whh + (size_t)(u)       * HS + koff;
        const float* rF = Whh + (size_t)(128 + u) * HS + koff;
        const float* rG = Whh + (size_t)(256 + u) * HS + koff;
        const float* rO = Whh + (size_t)(384 + u) * HS + koff;
        #pragma unroll
        for (int i = 0; i < 32; i++) {
            wI[i] = pack2(rI[2 * i], rI[2 * i + 1]);
            wF[i] = pack2(rF[2 * i], rF[2 * i + 1]);
            wG[i] = pack2(rG[2 * i], rG[2 * i + 1]);
            wO[i] = pack2(rO[2 * i], rO[2 * i + 1]);
        }
    }

    __shared__ alignas(16) _Float16 hsh[2][HS];
    float c = 0.f, h = 0.f;
    if (!lo) c = c0[b * HS + u];               // hi lanes own the c state
    if (tid < 128) hsh[0][tid] = (_Float16)h0[b * HS + tid];
    __syncthreads();

    const half2v* xwrow = xw + (size_t)b * SS * 256 + tid;
    half2v xb0 = xwrow[0];
    half2v xb1 = xwrow[256];
    half2v xb2 = xwrow[512];
    half2v xb3 = xwrow[768];

// one LSTM step. XB: prefetch reg holding xw(t); RB: LDS read buffer (0/1,
// compile-time); TN: step to prefetch into XB (t+4, used 4 steps later).
#define LSTEP(XB, RB, TN)                                                      \
    {                                                                          \
        const half2v* hb = (const half2v*)hsh[RB] + kv;                        \
        half2v hr[32];                                                         \
        _Pragma("unroll")                                                      \
        for (int j_ = 0; j_ < 32; j_++) hr[j_] = hb[j_];                       \
        float pI = 0.f, pF = 0.f, pG = 0.f, pO = 0.f;                          \
        _Pragma("unroll")                                                      \
        for (int j_ = 0; j_ < 32; j_++) {                                      \
            half2v hv = hr[j_];                                                \
            pI = fdot2f(hv, wI[j_], pI);                                       \
            pF = fdot2f(hv, wF[j_], pF);                                       \
            pG = fdot2f(hv, wG[j_], pG);                                       \
            pO = fdot2f(hv, wO[j_], pO);                                       \
        }                                                                      \
        /* exchange partials with lane^32 partner (proven primitive) */        \
        float r1 = __shfl_xor(lo ? pF : pI, 32, 64); /* lo: pI_hi | hi: pF_lo */\
        float r2 = __shfl_xor(lo ? pO : pG, 32, 64); /* lo: pG_hi | hi: pO_lo */\
        float pre0 = (lo ? pI : pF) + r1 + (float)XB.x;                        \
        float pre1 = (lo ? pG : pO) + r2 + (float)XB.y;                        \
        float act0 = sigm(pre0);                    /* lo: i | hi: f */        \
        float act1 = lo ? ftanh(pre1) : sigm(pre1); /* lo: g | hi: o */        \
        float pig = __shfl_xor(act0 * act1, 32, 64); /* hi receives i*g */     \
        if (!lo) {                                                             \
            c = __builtin_fmaf(act0, c, pig);                                  \
            h = act1 * ftanh(c);                                               \
            hsh[RB ^ 1][u] = (_Float16)h;                                      \
        }                                                                      \
        {                                                                      \
            int tn_ = (TN) < SS ? (TN) : (SS - 1);                             \
            XB = xwrow[(size_t)tn_ * 256];                                     \
        }                                                                      \
        asm volatile("s_waitcnt lgkmcnt(0)" ::: "memory");                     \
        __builtin_amdgcn_s_barrier();                                          \
        __builtin_amdgcn_sched_barrier(0);                                     \
    }

    for (int t = 0; t < SS; t += 4) {
        LSTEP(xb0, 0, t + 4)
        LSTEP(xb1, 1, t + 5)
        LSTEP(xb2, 0, t + 6)
        LSTEP(xb3, 1, t + 7)
    }
#undef LSTEP

    if (!lo) hfin[b * HS + u] = h;
}

// ---------------------------------------------------------------------------
// K3 (fallback, ws too small for xW)
// ---------------------------------------------------------------------------
__global__ __launch_bounds__(256, 1) void k_lstm_fb(
    const float* __restrict__ emb, const float* __restrict__ h0,
    const float* __restrict__ c0, const float* __restrict__ Wih,
    const float* __restrict__ Whh, const float* __restrict__ bih,
    const float* __restrict__ bhh, float* __restrict__ hfin)
{
    int b = blockIdx.x;
    int tid = threadIdx.x;

    half2v wih[2][32], whh[2][64];
    #pragma unroll
    for (int g = 0; g < 2; g++) {
        int gg = tid + g * 256;
        const float* wr = Wih + (size_t)gg * INS;
        #pragma unroll
        for (int i = 0; i < 32; i++) wih[g][i] = pack2(wr[2 * i], wr[2 * i + 1]);
        const float* hr = Whh + (size_t)gg * HS;
        #pragma unroll
        for (int i = 0; i < 64; i++) whh[g][i] = pack2(hr[2 * i], hr[2 * i + 1]);
    }
    float bias0 = bih[tid] + bhh[tid];
    float bias1 = bih[tid + 256] + bhh[tid + 256];

    __shared__ alignas(16) half2v xh[96];
    __shared__ float f_act[128], o_act[128];
    __shared__ float xf[64], hf[128];

    float c = 0.f, h = 0.f;
    if (tid < 128) c = c0[b * HS + tid];

    const float* xrow = emb + (size_t)b * SS * INS;
    if (tid < 64) xf[tid] = xrow[tid];
    if (tid < 128) hf[tid] = h0[b * HS + tid];
    __syncthreads();
    if (tid < 32) xh[tid] = pack2(xf[2 * tid], xf[2 * tid + 1]);
    else if (tid < 96) { int uu = tid - 32; xh[tid] = pack2(hf[2 * uu], hf[2 * uu + 1]); }
    __syncthreads();

    for (int t = 0; t < SS; t++) {
        float xn = 0.f;
        if (tid >= 128 && tid < 192 && t + 1 < SS) xn = xrow[(size_t)(t + 1) * INS + (tid - 128)];

        float a0a = 0.f, a0b = 0.f, a1a = 0.f, a1b = 0.f;
        #pragma unroll
        for (int i = 0; i < 32; i += 2) {
            half2v x0 = xh[i], x1 = xh[i + 1];
            a0a = fdot2f(x0, wih[0][i], a0a);
            a0b = fdot2f(x1, wih[0][i + 1], a0b);
            a1a = fdot2f(x0, wih[1][i], a1a);
            a1b = fdot2f(x1, wih[1][i + 1], a1b);
        }
        #pragma unroll
        for (int i = 0; i < 64; i += 2) {
            half2v h0v = xh[32 + i], h1v = xh[32 + i + 1];
            a0a = fdot2f(h0v, whh[0][i], a0a);
            a0b = fdot2f(h1v, whh[0][i + 1], a0b);
            a1a = fdot2f(h0v, whh[1][i], a1a);
            a1b = fdot2f(h1v, whh[1][i + 1], a1b);
        }
        float a0 = bias0 + a0a + a0b;
        float a1 = bias1 + a1a + a1b;

        float iact = 0.f, gact = 0.f;
        if (tid < 128) { iact = sigm(a0); gact = ftanh(a1); }
        else           { f_act[tid - 128] = sigm(a0); o_act[tid - 128] = sigm(a1); }
        __syncthreads();

        if (tid < 128) {
            c = f_act[tid] * c + iact * gact;
            h = o_act[tid] * ftanh(c);
            hf[tid] = h;
        } else if (tid < 192) {
            xf[tid - 128] = xn;
        }
        __syncthreads();

        if (tid < 32) xh[tid] = pack2(xf[2 * tid], xf[2 * tid + 1]);
        else if (tid < 96) { int uu = tid - 32; xh[tid] = pack2(hf[2 * uu], hf[2 * uu + 1]); }
        __syncthreads();
    }
    if (tid < 128) hfin[b * HS + tid] = h;
}

// ---------------------------------------------------------------------------
// K4: decoder logits + T=1e-3 softmax + freq-rec head. one block per b.
// ---------------------------------------------------------------------------
__global__ __launch_bounds__(256) void k_head(
    const float* __restrict__ hfin, const float* __restrict__ decW,
    const float* __restrict__ decB, const float* __restrict__ ad_emb,
    const float* __restrict__ encW, const float* __restrict__ encB,
    const float* __restrict__ dist, const float* __restrict__ fc1W,
    const float* __restrict__ fc1b, const float* __restrict__ fc2W,
    const float* __restrict__ fc2b, float* __restrict__ outp)
{
    int b = blockIdx.x;
    int tid = threadIdx.x;
    __shared__ float hsh[128];
    __shared__ float logit_s[4][256];
    __shared__ float probs_s[4][256];
    __shared__ float be_s[128];
    __shared__ float fe_dist[96];
    __shared__ float fr1[10];

    if (tid < 128) hsh[tid] = hfin[b * HS + tid];
    __syncthreads();

    #pragma unroll
    for (int k = 0; k < 4; k++) {
        const float* w = decW + ((size_t)k * OUTS + tid) * HS;
        float acc = decB[k * OUTS + tid];
        #pragma unroll 8
        for (int hh = 0; hh < HS; hh++) acc += hsh[hh] * w[hh];
        logit_s[k][tid] = acc;
        outp[65536 + k * 16384 + b * 256 + tid] = acc;
    }
    __syncthreads();

    {
        int k = tid >> 6, lane = tid & 63;
        float v0 = logit_s[k][lane],       v1 = logit_s[k][lane + 64];
        float v2 = logit_s[k][lane + 128], v3 = logit_s[k][lane + 192];
        float m = fmaxf(fmaxf(v0, v1), fmaxf(v2, v3));
        for (int off = 32; off; off >>= 1) m = fmaxf(m, __shfl_xor(m, off, 64));
        float e0 = fexp2((v0 - m) * 1442.695041f), e1 = fexp2((v1 - m) * 1442.695041f);
        float e2 = fexp2((v2 - m) * 1442.695041f), e3 = fexp2((v3 - m) * 1442.695041f);
        float s = e0 + e1 + e2 + e3;
        for (int off = 32; off; off >>= 1) s += __shfl_xor(s, off, 64);
        float inv = 1.f / s;
        float p0 = e0 * inv, p1 = e1 * inv, p2 = e2 * inv, p3 = e3 * inv;
        probs_s[k][lane] = p0;        probs_s[k][lane + 64] = p1;
        probs_s[k][lane + 128] = p2;  probs_s[k][lane + 192] = p3;
        outp[k * 16384 + b * 256 + lane] = p0;
        outp[k * 16384 + b * 256 + lane + 64] = p1;
        outp[k * 16384 + b * 256 + lane + 128] = p2;
        outp[k * 16384 + b * 256 + lane + 192] = p3;
    }
    __syncthreads();

    if (tid < 128) {
        int k = tid >> 5, e = tid & 31;
        const float* te = ad_emb + (size_t)k * OUTS * EMBS + e;
        float acc = 0.f;
        #pragma unroll 8
        for (int o = 0; o < OUTS; o++) acc += probs_s[k][o] * te[o * EMBS];
        be_s[tid] = acc;
    }
    __syncthreads();

    if (tid < 32) {
        const float* w = encW + tid * 128;
        float acc = encB[tid];
        #pragma unroll 8
        for (int kk = 0; kk < 128; kk++) acc += be_s[kk] * w[kk];
        fe_dist[tid] = sigm(acc);
    } else if (tid < 96) {
        fe_dist[tid] = dist[b * 64 + (tid - 32)];
    }
    __syncthreads();

    if (tid < 10) {
        float acc = fc1b[tid];
        for (int kk = 0; kk < 96; kk++) acc += fe_dist[kk] * fc1W[tid * 96 + kk];
        fr1[tid] = fmaxf(acc, 0.f);
    }
    __syncthreads();

    if (tid < 2) {
        float acc = fc2b[tid];
        for (int kk = 0; kk < 10; kk++) acc += fr1[kk] * fc2W[tid * 10 + kk];
        outp[131072 + tid * 64 + b] = sigm(acc);
    }
}

// ---------------------------------------------------------------------------
extern "C" void kernel_launch(void* const* d_in, const int* in_sizes, int n_in,
                              void* d_out, int out_size, void* d_ws, size_t ws_size,
                              hipStream_t stream)
{
    const int*   inp    = (const int*)d_in[0];
    const float* h0     = (const float*)d_in[1];
    const float* c0     = (const float*)d_in[2];
    const float* pc_emb = (const float*)d_in[3];
    const float* ad_emb = (const float*)d_in[4];
    const float* encW   = (const float*)d_in[5];
    const float* encB   = (const float*)d_in[6];
    const float* Wih    = (const float*)d_in[7];
    const float* Whh    = (const float*)d_in[8];
    const float* bih    = (const float*)d_in[9];
    const float* bhh    = (const float*)d_in[10];
    const float* decW   = (const float*)d_in[11];
    const float* decB   = (const float*)d_in[12];
    const float* fc1W   = (const float*)d_in[13];
    const float* fc1b   = (const float*)d_in[14];
    const float* fc2W   = (const float*)d_in[15];
    const float* fc2b   = (const float*)d_in[16];

    if (ws_size < WS_SMALL * 4ull) return;

    float* ws   = (float*)d_ws;
    float* emb  = ws;
    float* dist = ws + WS_DIST;
    float* hfin = ws + WS_HFIN;
    float* outp = (float*)d_out;
    bool big = (ws_size >= WS_BIG * 4ull);

    hipLaunchKernelGGL(k_embed, dim3(512), dim3(256), 0, stream,
                       inp, pc_emb, ad_emb, encW, encB, emb);
    hipLaunchKernelGGL(k_dist, dim3(64), dim3(256), 0, stream, emb, dist);
    if (big) {
        half2v* xwv = (half2v*)(ws + WS_XW);
        hipLaunchKernelGGL(k_xw, dim3(BS * SS / XW_ROWS), dim3(256), 0, stream,
                           emb, Wih, bih, bhh, xwv);
        hipLaunchKernelGGL(k_lstm6, dim3(64), dim3(256), 0, stream,
                           xwv, h0, c0, Whh, hfin);
    } else {
        hipLaunchKernelGGL(k_lstm_fb, dim3(64), dim3(256), 0, stream,
                           emb, h0, c0, Wih, Whh, bih, bhh, hfin);
    }
    hipLaunchKernelGGL(k_head, dim3(64), dim3(256), 0, stream,
                       hfin, decW, decB, ad_emb, encW, encB, dist,
                       fc1W, fc1b, fc2W, fc2b, outp);
}